// Round 5
// baseline (482.162 us; speedup 1.0000x reference)
//
#include <hip/hip_runtime.h>

// Problem constants (from reference)
#define B_     8
#define L_DEC_ 256
#define V_     32000
#define L_SRC_ 512
#define V_EXT_ 32128

#define V4_    (V_ / 4)        // 8000 float4 per dist row
#define VE4_   (V_EXT_ / 4)    // 8032 float4 per out row

#define NMAIN_   15            // k=0..14: i in [0,7680), fully inside dist
#define TAIL_I0_ (NMAIN_ * 512)      // 7680
#define TAIL_N_  (VE4_ - TAIL_I0_)   // 352 active threads in tail
#define TAIL_ND_ (V4_  - TAIL_I0_)   // 320 of them still inside dist

// Workspace layout: int offs[B_][513] ; unsigned ent[B_][512]
#define WS_OFFS_INTS_ (B_ * 513)
#define WS_BYTES_     (WS_OFFS_INTS_ * 4 + B_ * 512 * 4)

typedef float f32x4 __attribute__((ext_vector_type(4)));

// ---------------------------------------------------------------------------
// Kernel A: per-batch scatter pack. pointer[b,s] is t-invariant, so the
// bucket-by-owner-thread structure is computed ONCE per b (8 blocks) instead
// of once per (b,t) row (2048x redundant in v1-v4). CSR per (b, owner):
// owner of vocab v is float4-slot (v>>2) % 512.
// ---------------------------------------------------------------------------
__global__ __launch_bounds__(512) void scatter_pack(
    const int* __restrict__ pointer,   // [B, L_SRC]
    int*       __restrict__ offs_g,    // [B][513]
    unsigned*  __restrict__ ent_g)     // [B][512] packed v | (s<<16)
{
    __shared__ int cnt[512];
    __shared__ int sc[512];
    const int b   = blockIdx.x;
    const int tid = threadIdx.x;

    cnt[tid] = 0;
    __syncthreads();
    const int v     = pointer[b * L_SRC_ + tid];
    const int owner = (v >> 2) & 511;
    const int slot  = atomicAdd(&cnt[owner], 1);   // within-owner ordinal
    __syncthreads();

    // Hillis-Steele inclusive scan of cnt -> sc
    sc[tid] = cnt[tid];
    __syncthreads();
    for (int d = 1; d < 512; d <<= 1) {
        const int x = (tid >= d) ? sc[tid - d] : 0;
        __syncthreads();
        sc[tid] += x;
        __syncthreads();
    }

    offs_g[b * 513 + tid] = sc[tid] - cnt[tid];    // exclusive offset
    if (tid == 511) offs_g[b * 513 + 512] = sc[511];  // == 512

    const int base = sc[owner] - cnt[owner];       // owner's exclusive offset
    ent_g[b * 512 + base + slot] = (unsigned)v | ((unsigned)tid << 16);
}

// ---------------------------------------------------------------------------
// Kernel B: pure stream + rare-hit merge. No LDS, no barriers, no atomics,
// no uncoalesced gathers in the prologue — maximally copy-like.
//   out[b,t,v] = pg*dist[v] (v<V, else 0) + (1-pg)*alpha[b,s,t] summed over
//   CSR entries s with pointer[b,s]==v.
// ---------------------------------------------------------------------------
__global__ __launch_bounds__(512, 4) void copynet_stream(
    const float*    __restrict__ dist,    // [B, L_DEC, V]
    const float*    __restrict__ p_gen,   // [B, L_DEC, 1]
    const float*    __restrict__ alph,    // [B, L_SRC, L_DEC]
    const int*      __restrict__ offs_g,  // [B][513]
    const unsigned* __restrict__ ent_g,   // [B][512]
    float*          __restrict__ out)     // [B, L_DEC, V_EXT]
{
    const int row = blockIdx.x;           // b*L_DEC + t (t fastest -> alpha L2 reuse)
    const int b   = row >> 8;
    const int t   = row & (L_DEC_ - 1);
    const int tid = threadIdx.x;

    const float pg   = p_gen[row];
    const float coef = 1.0f - pg;

    // CSR slice for this owner thread (avg 1 entry, L2-hot 33 KB structure).
    const int off = offs_g[b * 513 + tid];
    const int end = offs_g[b * 513 + tid + 1];

    const unsigned* entB  = ent_g + b * 512;
    const float*    alphB = alph + ((size_t)b * L_SRC_) * L_DEC_ + t; // + s*256

    unsigned mask = 0u;                   // bit k: hit in stream iteration k
    for (int e = off; e < end; ++e)
        mask |= 1u << ((entB[e] >> 11) & 15);   // k = v>>11

    const f32x4* dist4 = (const f32x4*)(dist + (size_t)row * V_);
    f32x4*       out4  = (f32x4*)(out + (size_t)row * V_EXT_);

    // Branch-free main stream. NT load: dist is read-once, keep L2 for
    // out lines / alpha / CSR. 128-VGPR budget (launch_bounds 512,4) lets
    // the compiler keep many loads in flight without spilling.
#pragma unroll
    for (int k = 0; k < NMAIN_; ++k) {
        const int i = tid + (k << 9);
        f32x4 r = __builtin_nontemporal_load(dist4 + i) * pg;
        if (mask & (1u << k)) {           // rare: ~1 hit/thread across all k
            for (int e = off; e < end; ++e) {
                const unsigned ev = entB[e];
                const int v = (int)(ev & 0xffffu);
                if ((v >> 2) == i) {
                    const float a = coef * alphB[(ev >> 16) * L_DEC_];
                    const int   c = v & 3;
                    r.x += (c == 0) ? a : 0.f;
                    r.y += (c == 1) ? a : 0.f;
                    r.z += (c == 2) ? a : 0.f;
                    r.w += (c == 3) ? a : 0.f;
                }
            }
        }
        out4[i] = r;
    }

    // Peeled tail (k = 15): dist/pad boundary and row end both live here.
    if (tid < TAIL_N_) {
        const int i = TAIL_I0_ + tid;
        f32x4 r = {0.f, 0.f, 0.f, 0.f};
        if (tid < TAIL_ND_)
            r = __builtin_nontemporal_load(dist4 + i) * pg;
        if (mask & (1u << 15)) {
            for (int e = off; e < end; ++e) {
                const unsigned ev = entB[e];
                const int v = (int)(ev & 0xffffu);
                if ((v >> 2) == i) {
                    const float a = coef * alphB[(ev >> 16) * L_DEC_];
                    const int   c = v & 3;
                    r.x += (c == 0) ? a : 0.f;
                    r.y += (c == 1) ? a : 0.f;
                    r.z += (c == 2) ? a : 0.f;
                    r.w += (c == 3) ? a : 0.f;
                }
            }
        }
        out4[i] = r;
    }
}

// ---------------------------------------------------------------------------
// Fallback (ws too small): v3-style single fused kernel. Defensive only.
// ---------------------------------------------------------------------------
__global__ __launch_bounds__(512) void copynet_fused_fallback(
    const float* __restrict__ dist, const float* __restrict__ p_gen,
    const float* __restrict__ alph, const int* __restrict__ pointer,
    float* __restrict__ out)
{
    __shared__ int   head[512];
    __shared__ int   nxt[512];
    __shared__ int   key[512];
    __shared__ float sval[512];

    const int row = blockIdx.x, b = row >> 8, t = row & (L_DEC_ - 1);
    const int tid = threadIdx.x;
    const float pg = p_gen[row], coef = 1.0f - pg;

    const int   sIdx = b * L_SRC_ + tid;
    const int   v    = pointer[sIdx];
    const float val  = coef * alph[(size_t)sIdx * L_DEC_ + t];

    head[tid] = -1;
    __syncthreads();
    key[tid] = v; sval[tid] = val;
    nxt[tid] = atomicExch(&head[(v >> 2) & 511], tid);
    __syncthreads();

    const int myHead = head[tid];
    const f32x4* dist4 = (const f32x4*)(dist + (size_t)row * V_);
    f32x4*       out4  = (f32x4*)(out + (size_t)row * V_EXT_);

    for (int i = tid; i < VE4_; i += 512) {
        f32x4 r = {0.f, 0.f, 0.f, 0.f};
        if (i < V4_) r = dist4[i] * pg;
        for (int e = myHead; e != -1; e = nxt[e]) {
            const int kv = key[e];
            if ((kv >> 2) == i) {
                const float a = sval[e];
                const int   c = kv & 3;
                r.x += (c == 0) ? a : 0.f;
                r.y += (c == 1) ? a : 0.f;
                r.z += (c == 2) ? a : 0.f;
                r.w += (c == 3) ? a : 0.f;
            }
        }
        out4[i] = r;
    }
}

extern "C" void kernel_launch(void* const* d_in, const int* in_sizes, int n_in,
                              void* d_out, int out_size, void* d_ws, size_t ws_size,
                              hipStream_t stream)
{
    const float* dist    = (const float*)d_in[0]; // (B, L_DEC, V)
    const float* p_gen   = (const float*)d_in[1]; // (B, L_DEC, 1)
    const float* alph    = (const float*)d_in[2]; // (B, L_SRC, L_DEC)
    // d_in[3] = batch_vocab (shape only)
    const int*   pointer = (const int*)d_in[4];   // (B, L_SRC)
    float* out = (float*)d_out;                   // (B, L_DEC, V_EXT)

    if (d_ws != nullptr && ws_size >= (size_t)WS_BYTES_) {
        int*      offs_g = (int*)d_ws;
        unsigned* ent_g  = (unsigned*)((char*)d_ws + WS_OFFS_INTS_ * 4);
        scatter_pack<<<B_, 512, 0, stream>>>(pointer, offs_g, ent_g);
        copynet_stream<<<B_ * L_DEC_, 512, 0, stream>>>(
            dist, p_gen, alph, offs_g, ent_g, out);
    } else {
        copynet_fused_fallback<<<B_ * L_DEC_, 512, 0, stream>>>(
            dist, p_gen, alph, pointer, out);
    }
}

// Round 6
// 443.597 us; speedup vs baseline: 1.0869x; 1.0869x over previous
//
#include <hip/hip_runtime.h>

// Problem constants (from reference)
#define B_     8
#define L_DEC_ 256
#define V_     32000
#define L_SRC_ 512
#define V_EXT_ 32128

#define V4_    (V_ / 4)        // 8000 float4 per dist row
#define VE4_   (V_EXT_ / 4)    // 8032 float4 per out row

#define ROWS_  4               // t-rows per block (prologue amortization)

// Native clang vector type (nontemporal builtins reject HIP's float4 struct).
typedef float f32x4 __attribute__((ext_vector_type(4)));

// Fused kernel, one block per (b, t-quad):
//   out[b,t,v] = pg[t]*dist[b,t,v] (v<V, else 0) + (1-pg[t])*copyp[b,t,v]
//   copyp[b,t,v] = sum_{s: pointer[b,s]==v} alpha[b,s,t]
//
// v6: v3's proven hot loop (117 us kernel) untouched; the per-row prologue
// (pointer load, alpha gather, LDS bucket build, barriers, mask build) now
// runs once per 4 rows instead of once per row (2048x -> 512x), and the
// alpha gather is a single coalesced-granule f32x4 load covering all 4 rows.
// v5's lesson applied: scatter operands are LDS-resident BEFORE the stream.
__global__ __launch_bounds__(512) void copynet_fused(
    const float* __restrict__ dist,    // [B, L_DEC, V]
    const float* __restrict__ p_gen,   // [B, L_DEC, 1]
    const float* __restrict__ alph,    // [B, L_SRC, L_DEC]
    const int*   __restrict__ pointer, // [B, L_SRC]
    float* __restrict__ out)           // [B, L_DEC, V_EXT]
{
    __shared__ int   head[512];        // per-owner-thread list head (-1 = empty)
    __shared__ int   nxt[512];         // linkage, indexed by entry id (= s)
    __shared__ int   key[512];         // vocab index v of entry
    __shared__ float sval[ROWS_][512]; // (1-pg[t0+r]) * alpha[b,s,t0+r]

    const int bid = blockIdx.x;        // b*64 + tq  (tq fastest -> alpha L2 reuse)
    const int b   = bid >> 6;          // / (L_DEC_/ROWS_)
    const int t0  = (bid & 63) << 2;   // first of 4 consecutive t-rows
    const int tid = threadIdx.x;       // 0..511

    // 4 rows' p_gen in one 16B load ([B, L_DEC, 1] is contiguous).
    const f32x4 pgv = *(const f32x4*)(p_gen + b * L_DEC_ + t0);

    // This thread's scatter entry: s == tid. One 16B load covers the 4 rows'
    // alpha values (alph row stride = 256 floats; t0 is 16B-aligned).
    const int   sIdx = b * L_SRC_ + tid;
    const int   v    = pointer[sIdx];
    const f32x4 av   = *(const f32x4*)(alph + (size_t)sIdx * L_DEC_ + t0);

    // Bucket the 512 (v, val[4]) entries by owner thread of slot v>>2.
    head[tid] = -1;
    __syncthreads();
    key[tid]     = v;
    sval[0][tid] = (1.0f - pgv.x) * av.x;
    sval[1][tid] = (1.0f - pgv.y) * av.y;
    sval[2][tid] = (1.0f - pgv.z) * av.z;
    sval[3][tid] = (1.0f - pgv.w) * av.w;
    nxt[tid] = atomicExch(&head[(v >> 2) & 511], tid);  // lock-free stack push
    __syncthreads();

    const int myHead = head[tid];      // immutable after barrier
    unsigned mask = 0u;                // bit k: this thread has a hit in iter k
    for (int e = myHead; e != -1; e = nxt[e])
        mask |= 1u << (key[e] >> 11);  // k = (v>>2) >> 9

    // Stream 4 rows with the proven v3 loop. #pragma unroll keeps sval/pgv
    // indices compile-time (rule: runtime-indexed ext_vector -> scratch).
#pragma unroll
    for (int r = 0; r < ROWS_; ++r) {
        const int row = b * L_DEC_ + t0 + r;
        const float pg = (r == 0) ? pgv.x : (r == 1) ? pgv.y
                                          : (r == 2) ? pgv.z : pgv.w;
        const f32x4* dist4 = (const f32x4*)(dist + (size_t)row * V_);
        f32x4*       out4  = (f32x4*)(out + (size_t)row * V_EXT_);

        for (int i = tid; i < VE4_; i += 512) {
            f32x4 rr;
            if (i < V4_) {
                rr = __builtin_nontemporal_load(dist4 + i) * pg;
            } else {
                rr = (f32x4){0.f, 0.f, 0.f, 0.f};   // pad region: copyp only
            }
            if (mask & (1u << (i >> 9))) {          // rare (~1 hit/thread total)
                for (int e = myHead; e != -1; e = nxt[e]) {
                    const int kv = key[e];
                    if ((kv >> 2) == i) {
                        const float a = sval[r][e];
                        const int   c = kv & 3;
                        rr.x += (c == 0) ? a : 0.f;
                        rr.y += (c == 1) ? a : 0.f;
                        rr.z += (c == 2) ? a : 0.f;
                        rr.w += (c == 3) ? a : 0.f;
                    }
                }
            }
            __builtin_nontemporal_store(rr, out4 + i);
        }
    }
}

extern "C" void kernel_launch(void* const* d_in, const int* in_sizes, int n_in,
                              void* d_out, int out_size, void* d_ws, size_t ws_size,
                              hipStream_t stream)
{
    const float* dist    = (const float*)d_in[0]; // (B, L_DEC, V)
    const float* p_gen   = (const float*)d_in[1]; // (B, L_DEC, 1)
    const float* alph    = (const float*)d_in[2]; // (B, L_SRC, L_DEC)
    // d_in[3] = batch_vocab (shape only)
    const int*   pointer = (const int*)d_in[4];   // (B, L_SRC)
    float* out = (float*)d_out;                   // (B, L_DEC, V_EXT)

    copynet_fused<<<B_ * (L_DEC_ / ROWS_), 512, 0, stream>>>(
        dist, p_gen, alph, pointer, out);
}